// Round 3
// baseline (710.714 us; speedup 1.0000x reference)
//
#include <hip/hip_runtime.h>

// ParabolicPool2D, vertical-first fused form. (Resubmission: round-2 bench was an
// infra failure — "container failed twice" — no kernel verdict; source re-audited, unchanged.)
// out[b,c,i,j] = max_{u,v} f[b,c,2i+u-3,2j+v-3] + hu[u] + hu[v],  hu[k] = -(k-3)^2/(4t)
// Pass A (global->reg->LDS): v[i][x] = max_u f[2(i0+i)+u-3][x] + hu[u]   (full 256-wide rows,
//   unconditional clamped loads, y-OOB handled by masking hu to -inf -> 9-deep MLP, no divergence)
// Pass B (LDS->global): out[i][j] = max_u v[i][2j+u-3] + hu[u]           (x-pad cols are -inf)
// hu symmetric (h[3]=0): 7-way max-plus costs 3 max + 3 add + 3 max.

#define H 256
#define W 256
#define HO 128
#define WO 128
#define TH 16               // output rows per block (strip)
#define VPAD 4              // -inf pad columns each side of v rows
#define VSTRIDE 276         // floats per v row; (276%32)=20 -> all b128 accesses bank-balanced

__device__ __forceinline__ float4 f4max(float4 a, float4 b) {
    return make_float4(fmaxf(a.x, b.x), fmaxf(a.y, b.y), fmaxf(a.z, b.z), fmaxf(a.w, b.w));
}
__device__ __forceinline__ float4 f4adds(float4 a, float s) {
    return make_float4(a.x + s, a.y + s, a.z + s, a.w + s);
}

__global__ __launch_bounds__(512, 6)
void pp_kernel(const float* __restrict__ f, const float* __restrict__ tptr,
               float* __restrict__ out) {
    __shared__ __align__(16) float v_[TH * VSTRIDE];   // 17664 B

    const int tid = threadIdx.x;
    const int bid = blockIdx.x;
    // 16384 blocks, 8 XCDs, 2048/XCD: bijective swizzle; consecutive lids on one XCD are
    // consecutive strips of the same plane -> y-halo rows hit that XCD's L2.
    const int lid   = (bid & 7) * 2048 + (bid >> 3);
    const int plane = lid >> 3;          // b*128 + c
    const int strip = lid & 7;
    const int i0    = strip * TH;

    const float tv  = tptr[0];
    const float inv = 1.0f / (4.0f * tv);
    const float h0 = -9.0f * inv, h1 = -4.0f * inv, h2 = -1.0f * inv;  // h3 = 0
    const float NEG = -__builtin_inff();

    const float* __restrict__ fplane = f + (size_t)plane * (H * W);

    // x-pad columns: v cols [-4,-1] and [256,259] = -inf (raw float idx 0..3 and 260..263)
    if (tid < 32) {
        const int r   = tid & 15;
        const int off = (tid < 16) ? 0 : (VPAD + W);
        *(float4*)(&v_[r * VSTRIDE + off]) = make_float4(NEG, NEG, NEG, NEG);
    }

    // ---- Pass A: one item per thread: (x4 column group) x (pair of output rows) ----
    {
        const int x4    = (tid & 63) * 4;        // float col 0..252 (full row, f4-aligned)
        const int ipair = tid >> 6;              // 0..7 (wave-uniform)
        const int ib    = 2 * ipair;             // tile-local out rows ib, ib+1
        const int gy0   = 2 * (i0 + ib) - 3;     // first of 9 input rows (wave-uniform)

        float4 r[9];
#pragma unroll
        for (int k = 0; k < 9; ++k) {
            const int cy = min(max(gy0 + k, 0), H - 1);     // clamped: always-valid address
            r[k] = *(const float4*)(fplane + cy * W + x4);  // wave: contiguous 1KB, coalesced
        }

        float4 vA, vB;
        if (gy0 >= 0 && gy0 + 8 <= H - 1) {
            // interior fast path (wave-uniform branch), symmetric kernel
            vA = f4max(f4max(f4adds(f4max(r[0], r[6]), h0),
                             f4adds(f4max(r[1], r[5]), h1)),
                       f4max(f4adds(f4max(r[2], r[4]), h2), r[3]));
            vB = f4max(f4max(f4adds(f4max(r[2], r[8]), h0),
                             f4adds(f4max(r[3], r[7]), h1)),
                       f4max(f4adds(f4max(r[4], r[6]), h2), r[5]));
        } else {
            const float hu[7] = {h0, h1, h2, 0.0f, h2, h1, h0};
            float4 a = make_float4(NEG, NEG, NEG, NEG);
            float4 b = make_float4(NEG, NEG, NEG, NEG);
#pragma unroll
            for (int u = 0; u < 7; ++u) {
                const int gyA = gy0 + u;
                const int gyB = gy0 + 2 + u;
                const float hA = (gyA >= 0 && gyA < H) ? hu[u] : NEG;
                const float hB = (gyB >= 0 && gyB < H) ? hu[u] : NEG;
                a = f4max(a, f4adds(r[u], hA));
                b = f4max(b, f4adds(r[u + 2], hB));
            }
            vA = a; vB = b;
        }

        *(float4*)(&v_[(ib)     * VSTRIDE + VPAD + x4]) = vA;
        *(float4*)(&v_[(ib + 1) * VSTRIDE + VPAD + x4]) = vB;
    }
    __syncthreads();

    // ---- Pass B: horizontal max-plus from LDS, 4 outputs per thread ----
    {
        const int i  = tid >> 5;                 // 0..15 (out row, tile-local)
        const int jg = tid & 31;                 // 0..31 -> out cols 4jg..4jg+3
        const int c0 = 4 * jg;
        const float* p = &v_[i * VSTRIDE + 2 * c0];   // raw idx 8jg, f4-aligned
        const float4 a = *(const float4*)(p);
        const float4 b = *(const float4*)(p + 4);
        const float4 c = *(const float4*)(p + 8);
        const float4 d = *(const float4*)(p + 12);
        const float s[16] = {a.x, a.y, a.z, a.w, b.x, b.y, b.z, b.w,
                             c.x, c.y, c.z, c.w, d.x, d.y, d.z, d.w};
        float4 o;
        float* op = (float*)&o;
#pragma unroll
        for (int dd = 0; dd < 4; ++dd) {
            // out col j = c0+dd needs raw s-window [2dd+1, 2dd+7]
            const float m0 = fmaxf(s[2 * dd + 1], s[2 * dd + 7]) + h0;
            const float m1 = fmaxf(s[2 * dd + 2], s[2 * dd + 6]) + h1;
            const float m2 = fmaxf(s[2 * dd + 3], s[2 * dd + 5]) + h2;
            op[dd] = fmaxf(fmaxf(m0, m1), fmaxf(m2, s[2 * dd + 4]));
        }
        float* __restrict__ orow = out + (size_t)plane * (HO * WO) + (size_t)(i0 + i) * WO;
        *(float4*)(orow + c0) = o;
    }
}

extern "C" void kernel_launch(void* const* d_in, const int* in_sizes, int n_in,
                              void* d_out, int out_size, void* d_ws, size_t ws_size,
                              hipStream_t stream) {
    const float* f = (const float*)d_in[0];
    const float* t = (const float*)d_in[1];
    float* out = (float*)d_out;
    // 2048 planes x 8 row-strips, 512 threads (one balanced Pass-A item per thread)
    pp_kernel<<<dim3(2048 * 8), dim3(512), 0, stream>>>(f, t, out);
}